// Round 8
// baseline (209.455 us; speedup 1.0000x reference)
//
#include <hip/hip_runtime.h>
#include <hip/hip_bf16.h>

// SchNet CFConv, MI355X gfx950 — round 11: SOFTWARE-PIPELINED persistent cfconv.
// r10 showed ~28.5K cycles/atom vs ~5K of issued work: the per-atom chain
// (global loads -> stage1 -> barrier -> stage2 -> agg) is latency-bound.
// Fix: 2-deep pipeline per block — prefetch atom i+1's globals + compute its
// stage1 into registers while atom i's stage2/agg runs; LDS exchange happens
// in a short barrier-B..barrier-A window. dreb (r8-proven, ws>=33.4MB proven)
// supplies bf16-packed dRe: 3 aligned bf16x8 loads, 12 VGPR, no divergence.
// f2out separate (inline cost +10us, measured r5/r8). 3 dispatches.
//
// d_ws layout (unsigned short elements)  [identical to r8, proven]:
//   [0        .. 4096    )  W1T  bf16 [128 f][32 gpad]  (g>=25 zero)
//   [4096     .. 20480   )  W2T  bf16 [128 h][128 j]
//   [20480    .. 36864   )  WoT  bf16 [128 o][128 f]
//   [36864    .. 1316864 )  yfeatb bf16 [10000][128]
//   [1316864  .. 16676864)  dreb bf16 [10000][48][32]

#define NA 10000
#define NK 48
#define NF 128
#define HP  136   // s_H  row pad (bf16): 272 B rows -> 2-way (free)
#define YFP 136   // s_yf row pad (bf16)
#define GRID_CF 1024

typedef __bf16 bf16x8 __attribute__((ext_vector_type(8)));
typedef float  f32x4  __attribute__((ext_vector_type(4)));

__device__ __forceinline__ unsigned short f2bs(float x) {
    return __builtin_bit_cast(unsigned short, (__bf16)x);
}
__device__ __forceinline__ float bs2f(unsigned short u) {
    return (float)__builtin_bit_cast(__bf16, u);
}
__device__ __forceinline__ float sspf(float v) {
    return fmaxf(v, 0.0f) + __logf(1.0f + __expf(-fabsf(v))) - 0.69314718056f;
}

// ---- kernel 1: in2f MFMA (0..156) + weight prep (157..300) + dreb (301..1068) ----
__global__ __launch_bounds__(256) void in2f_prep(
    const float* __restrict__ x,
    const float* __restrict__ Wi,
    const float* __restrict__ W1,
    const float* __restrict__ W2,
    const float* __restrict__ Wo,
    const float* __restrict__ dRe,
    unsigned short* __restrict__ wsb,
    unsigned short* __restrict__ yfeatb,
    unsigned short* __restrict__ dreb)
{
    const int tid = threadIdx.x;

    if (blockIdx.x >= 301) {
        // ---- dreb transform (r8-proven): 3,000,000 float4 grid-stride ----
        const float4* src = (const float4*)dRe;
        for (int j = (blockIdx.x - 301) * 256 + tid; j < 3000000; j += 768 * 256) {
            float4 v = src[j];
            int n  = j / 300;
            int rm = j - n * 300;
            int i  = rm * 4;
            int k  = i / 25;
            int g  = i - k * 25;
            unsigned short* dst = dreb + (size_t)n * 1536;
            float vv[4] = {v.x, v.y, v.z, v.w};
            #pragma unroll
            for (int e = 0; e < 4; ++e) {
                dst[k * 32 + g] = f2bs(vv[e]);
                if (++g == 25) {
                    #pragma unroll
                    for (int p = 25; p < 32; ++p) dst[k * 32 + p] = 0;
                    g = 0; ++k;
                }
            }
        }
        return;
    }

    if (blockIdx.x >= 157) {
        int i = (blockIdx.x - 157) * 256 + tid;
        if (i < 4096) {                       // W1T[f][g], g padded to 32
            int f = i >> 5, g = i & 31;
            wsb[i] = (g < 25) ? f2bs(W1[g * NF + f]) : (unsigned short)0;
        } else if (i < 20480) {               // W2T[h][j]
            int j = i - 4096; int h = j >> 7, k = j & 127;
            wsb[i] = f2bs(W2[k * NF + h]);
        } else {                              // WoT[o][f]
            int j = i - 20480; int f = j >> 7, k = j & 127;
            wsb[i] = f2bs(Wo[k * NF + f]);
        }
        return;
    }

    // ---- in2f: block-local Wi -> LDS transpose, then MFMA ----
    __shared__ __align__(16) unsigned short s_wi[NF * 136];
    {
        const float4* wi4 = (const float4*)Wi;
        #pragma unroll
        for (int it = 0; it < 16; ++it) {
            int idx4 = it * 256 + tid;
            float4 v = wi4[idx4];
            int i = idx4 >> 5;
            int f = (idx4 & 31) * 4;
            s_wi[(f + 0) * 136 + i] = f2bs(v.x);
            s_wi[(f + 1) * 136 + i] = f2bs(v.y);
            s_wi[(f + 2) * 136 + i] = f2bs(v.z);
            s_wi[(f + 3) * 136 + i] = f2bs(v.w);
        }
    }
    __syncthreads();

    const int w = tid >> 6;
    const int lane = tid & 63;
    const int r = lane & 15;
    const int q = lane >> 4;
    const int m0 = blockIdx.x * 64 + w * 16;
    const int row = m0 + r;
    const bool rv = (row < NA);

    f32x4 acc[8];
    #pragma unroll
    for (int nt = 0; nt < 8; ++nt) { acc[nt][0]=0.f; acc[nt][1]=0.f; acc[nt][2]=0.f; acc[nt][3]=0.f; }

    #pragma unroll
    for (int ks = 0; ks < 4; ++ks) {
        bf16x8 a;
        if (rv) {
            const float4* xp = (const float4*)(x + (size_t)row * NF + ks * 32 + q * 8);
            float4 v0 = xp[0], v1 = xp[1];
            a[0]=(__bf16)v0.x; a[1]=(__bf16)v0.y; a[2]=(__bf16)v0.z; a[3]=(__bf16)v0.w;
            a[4]=(__bf16)v1.x; a[5]=(__bf16)v1.y; a[6]=(__bf16)v1.z; a[7]=(__bf16)v1.w;
        } else {
            #pragma unroll
            for (int j = 0; j < 8; ++j) a[j] = (__bf16)0.0f;
        }
        #pragma unroll
        for (int nt = 0; nt < 8; ++nt) {
            bf16x8 b = *(const bf16x8*)(&s_wi[(nt * 16 + r) * 136 + ks * 32 + q * 8]);
            acc[nt] = __builtin_amdgcn_mfma_f32_16x16x32_bf16(a, b, acc[nt], 0, 0, 0);
        }
    }
    #pragma unroll
    for (int nt = 0; nt < 8; ++nt) {
        #pragma unroll
        for (int reg = 0; reg < 4; ++reg) {
            int orow = m0 + q * 4 + reg;
            if (orow < NA)
                yfeatb[(size_t)orow * NF + nt * 16 + r] = f2bs(acc[nt][reg]);
        }
    }
}

// ---- kernel 2: pipelined persistent cfconv ----
__global__ __launch_bounds__(256, 4) void cfconv_pp(
    const float* __restrict__ dR,
    const float* __restrict__ mask,
    const int*   __restrict__ nbr,
    const float* __restrict__ b1,
    const float* __restrict__ b2,
    const unsigned short* __restrict__ W1T,
    const unsigned short* __restrict__ W2T,
    const unsigned short* __restrict__ dreb,
    const unsigned short* __restrict__ yfeatb,
    float* __restrict__ yout)
{
    __shared__ __align__(16) unsigned short s_H[NK * HP];    // 13056 B
    __shared__ __align__(16) unsigned short s_yf[NK * YFP];  // 13056 B
    __shared__ float s_cm[NK];                               // 192 B

    const int tid = threadIdx.x;
    const int w = tid >> 6;
    const int lane = tid & 63;
    const int r = lane & 15;
    const int q = lane >> 4;
    const int nt0 = w * 2;
    const int kb = tid >> 4;
    const int sp = tid & 15;

    // ---- hoisted weights/biases (amortized over all iterations) ----
    const bf16x8 bfr0 = *(const bf16x8*)(W1T + ((nt0    ) * 16 + r) * 32 + q * 8);
    const bf16x8 bfr1 = *(const bf16x8*)(W1T + ((nt0 + 1) * 16 + r) * 32 + q * 8);
    bf16x8 bw[2][4];
    #pragma unroll
    for (int t = 0; t < 2; ++t)
        #pragma unroll
        for (int ks = 0; ks < 4; ++ks)
            bw[t][ks] = *(const bf16x8*)(W2T + ((nt0 + t) * 16 + r) * NF + ks * 32 + q * 8);
    const float bias1a = b1[nt0 * 16 + r];
    const float bias1b = b1[nt0 * 16 + 16 + r];
    const float bias2a = b2[nt0 * 16 + r];
    const float bias2b = b2[nt0 * 16 + 16 + r];

    // ---- pipeline registers ----
    bf16x8 g0, g1, g2;          // gathered neighbor rows
    bf16x8 a0, a1, a2;          // dreb A-fragments
    float dv = 10.0f, mv = 0.0f;
    unsigned short hsv[24];     // stage1 output (bf16 bits), statically indexed

    auto prefetch = [&](int nn) {
        const int nb0 = nbr[nn * NK + kb] * NF;
        const int nb1 = nbr[nn * NK + kb + 16] * NF;
        const int nb2 = nbr[nn * NK + kb + 32] * NF;
        g0 = *(const bf16x8*)(yfeatb + nb0 + sp * 8);
        g1 = *(const bf16x8*)(yfeatb + nb1 + sp * 8);
        g2 = *(const bf16x8*)(yfeatb + nb2 + sp * 8);
        const unsigned short* dn = dreb + (size_t)nn * 1536;
        a0 = *(const bf16x8*)(dn + (     r) * 32 + q * 8);
        a1 = *(const bf16x8*)(dn + (16 + r) * 32 + q * 8);
        a2 = *(const bf16x8*)(dn + (32 + r) * 32 + q * 8);
        if (tid < NK) {
            dv = dR[nn * NK + tid];
            mv = mask[nn * NK + tid];
        }
    };

    auto stage1 = [&]() {
        #pragma unroll
        for (int mt = 0; mt < 3; ++mt) {
            bf16x8 av8 = (mt == 0) ? a0 : (mt == 1) ? a1 : a2;
            f32x4 zf; zf[0]=0.f; zf[1]=0.f; zf[2]=0.f; zf[3]=0.f;
            f32x4 h0v = __builtin_amdgcn_mfma_f32_16x16x32_bf16(av8, bfr0, zf, 0, 0, 0);
            f32x4 h1v = __builtin_amdgcn_mfma_f32_16x16x32_bf16(av8, bfr1, zf, 0, 0, 0);
            #pragma unroll
            for (int reg = 0; reg < 4; ++reg) {
                hsv[mt * 8 + reg]     = f2bs(sspf(h0v[reg] + bias1a));
                hsv[mt * 8 + 4 + reg] = f2bs(sspf(h1v[reg] + bias1b));
            }
        }
    };

    auto ldswrite = [&]() {
        #pragma unroll
        for (int mt = 0; mt < 3; ++mt) {
            #pragma unroll
            for (int reg = 0; reg < 4; ++reg) {
                int k = mt * 16 + q * 4 + reg;
                s_H[k * HP + nt0 * 16 + r]      = hsv[mt * 8 + reg];
                s_H[k * HP + nt0 * 16 + 16 + r] = hsv[mt * 8 + 4 + reg];
            }
        }
        *(bf16x8*)(&s_yf[(kb     ) * YFP + sp * 8]) = g0;
        *(bf16x8*)(&s_yf[(kb + 16) * YFP + sp * 8]) = g1;
        *(bf16x8*)(&s_yf[(kb + 32) * YFP + sp * 8]) = g2;
        if (tid < NK)
            s_cm[tid] = (dv <= 5.0f) ? mv : 0.0f;
    };

    // ---- prologue: fill pipeline for first atom ----
    int n = blockIdx.x;
    prefetch(n);
    stage1();
    ldswrite();
    __syncthreads();   // barrier A(0)

    while (true) {
        const int n_next = n + GRID_CF;
        const bool more = (n_next < NA);

        if (more) prefetch(n_next);   // issue next atom's globals early

        // ---- stage 2 for atom n: A2 = H @ W2 ----
        f32x4 acc[3][2];
        #pragma unroll
        for (int mt = 0; mt < 3; ++mt)
            #pragma unroll
            for (int t = 0; t < 2; ++t) { acc[mt][t][0]=0.f; acc[mt][t][1]=0.f; acc[mt][t][2]=0.f; acc[mt][t][3]=0.f; }

        #pragma unroll
        for (int ks = 0; ks < 4; ++ks) {
            #pragma unroll
            for (int mt = 0; mt < 3; ++mt) {
                bf16x8 ah = *(const bf16x8*)(&s_H[(mt * 16 + r) * HP + ks * 32 + q * 8]);
                acc[mt][0] = __builtin_amdgcn_mfma_f32_16x16x32_bf16(ah, bw[0][ks], acc[mt][0], 0, 0, 0);
                acc[mt][1] = __builtin_amdgcn_mfma_f32_16x16x32_bf16(ah, bw[1][ks], acc[mt][1], 0, 0, 0);
            }
        }

        if (more) stage1();           // next atom's stage1 (pure reg, overlaps)

        // ---- aggregation for atom n ----
        float part0 = 0.f, part1 = 0.f;
        const int h0 = nt0 * 16 + r;
        #pragma unroll
        for (int mt = 0; mt < 3; ++mt) {
            #pragma unroll
            for (int reg = 0; reg < 4; ++reg) {
                int k = mt * 16 + q * 4 + reg;
                float cmk = s_cm[k];
                part0 += cmk * (acc[mt][0][reg] + bias2a) * bs2f(s_yf[k * YFP + h0]);
                part1 += cmk * (acc[mt][1][reg] + bias2b) * bs2f(s_yf[k * YFP + h0 + 16]);
            }
        }
        part0 += __shfl_xor(part0, 16);
        part0 += __shfl_xor(part0, 32);
        part1 += __shfl_xor(part1, 16);
        part1 += __shfl_xor(part1, 32);
        if (q == 0) {
            yout[(size_t)n * NF + h0]      = part0;
            yout[(size_t)n * NF + h0 + 16] = part1;
        }

        if (!more) break;

        __syncthreads();   // barrier B: all reads of s_H/s_yf/s_cm done
        ldswrite();        // exchange window: dump next atom to LDS
        __syncthreads();   // barrier A: next atom's LDS ready
        n = n_next;
    }
}

// ---- kernel 3: f2out = ssp(y @ Wf2o + b), MFMA, IN PLACE on out ----
__global__ __launch_bounds__(256) void f2out_mfma(
    const unsigned short* __restrict__ WoT,
    const float* __restrict__ bo,
    float* io)
{
    const int tid = threadIdx.x;
    const int w = tid >> 6;
    const int lane = tid & 63;
    const int r = lane & 15;
    const int q = lane >> 4;
    const int m0 = blockIdx.x * 64 + w * 16;
    const int row = m0 + r;
    const bool rv = (row < NA);

    f32x4 acc[8];
    #pragma unroll
    for (int nt = 0; nt < 8; ++nt) { acc[nt][0]=0.f; acc[nt][1]=0.f; acc[nt][2]=0.f; acc[nt][3]=0.f; }

    #pragma unroll
    for (int ks = 0; ks < 4; ++ks) {
        bf16x8 a;
        if (rv) {
            const float4* yp = (const float4*)(io + (size_t)row * NF + ks * 32 + q * 8);
            float4 v0 = yp[0], v1 = yp[1];
            a[0]=(__bf16)v0.x; a[1]=(__bf16)v0.y; a[2]=(__bf16)v0.z; a[3]=(__bf16)v0.w;
            a[4]=(__bf16)v1.x; a[5]=(__bf16)v1.y; a[6]=(__bf16)v1.z; a[7]=(__bf16)v1.w;
        } else {
            #pragma unroll
            for (int j = 0; j < 8; ++j) a[j] = (__bf16)0.0f;
        }
        #pragma unroll
        for (int nt = 0; nt < 8; ++nt) {
            bf16x8 b = *(const bf16x8*)(WoT + (nt * 16 + r) * NF + ks * 32 + q * 8);
            acc[nt] = __builtin_amdgcn_mfma_f32_16x16x32_bf16(a, b, acc[nt], 0, 0, 0);
        }
    }
    #pragma unroll
    for (int nt = 0; nt < 8; ++nt) {
        float bia = bo[nt * 16 + r];
        #pragma unroll
        for (int reg = 0; reg < 4; ++reg) {
            int orow = m0 + q * 4 + reg;
            if (orow < NA)
                io[(size_t)orow * NF + nt * 16 + r] = sspf(acc[nt][reg] + bia);
        }
    }
}

extern "C" void kernel_launch(void* const* d_in, const int* in_sizes, int n_in,
                              void* d_out, int out_size, void* d_ws, size_t ws_size,
                              hipStream_t stream)
{
    const float* x    = (const float*)d_in[0];
    const float* dR   = (const float*)d_in[1];
    const float* dRe  = (const float*)d_in[2];
    const float* mask = (const float*)d_in[3];
    const int*   nbr  = (const int*)d_in[4];
    const float* W1   = (const float*)d_in[5];
    const float* b1   = (const float*)d_in[6];
    const float* W2   = (const float*)d_in[7];
    const float* b2   = (const float*)d_in[8];
    const float* Wi2f = (const float*)d_in[9];
    const float* Wf2o = (const float*)d_in[10];
    const float* bf2o = (const float*)d_in[11];
    float* out = (float*)d_out;

    unsigned short* wsb = (unsigned short*)d_ws;
    unsigned short* W1T    = wsb;              // 4096 elems
    unsigned short* W2T    = wsb + 4096;       // 16384 elems
    unsigned short* WoT    = wsb + 20480;      // 16384 elems
    unsigned short* yfeatb = wsb + 36864;      // 1,280,000 elems
    unsigned short* dreb   = wsb + 1316864;    // 15,360,000 elems (ws>=33.4MB proven in r8)

    in2f_prep<<<1069, 256, 0, stream>>>(x, Wi2f, W1, W2, Wf2o, dRe,
                                        wsb, yfeatb, dreb);
    cfconv_pp<<<GRID_CF, 256, 0, stream>>>(dR, mask, nbr, b1, b2,
                                           W1T, W2T, dreb, yfeatb, out);
    f2out_mfma<<<157, 256, 0, stream>>>(WoT, bf2o, out);
}